// Round 1
// baseline (549.619 us; speedup 1.0000x reference)
//
#include <hip/hip_runtime.h>
#include <hip/hip_bf16.h>

// Problem constants (fixed by the reference)
constexpr int M_ = 8192;      // batch
constexpr int N_ = 4096;      // out_dim
constexpr int K_ = 4096;      // in_dim
constexpr int CBOOK = 65536;
constexpr int HA = 10007, HB = 20011;
constexpr int HC3 = 3 * 40009;     // 120027
// sign hash: all constants odd => sign = +1 iff (o+i) even

constexpr int BM = 128, BN = 128, BK = 32;

using bf16x8 = __bf16 __attribute__((ext_vector_type(8)));
using f32x4  = float __attribute__((ext_vector_type(4)));
using u16x8  = unsigned short __attribute__((ext_vector_type(8)));

typedef __attribute__((address_space(3))) void lds_void_t;
typedef const __attribute__((address_space(1))) void gbl_void_t;

static __device__ __forceinline__ unsigned short f2bf(float f) {
    __bf16 h = (__bf16)f;   // RNE on gfx950
    return __builtin_bit_cast(unsigned short, h);
}

// ---------------------------------------------------------------------------
// W generation: W[o][i] = sign(o,i) * codebook[(o*HA + i*HB + HC3) & 0xFFFF]
// One thread -> 8 consecutive i (one 16B store). Codebook (256KB) is L2-hot.
// ---------------------------------------------------------------------------
__global__ __launch_bounds__(256) void gen_w_kernel(const float* __restrict__ cb,
                                                    unsigned short* __restrict__ W) {
    const int t  = blockIdx.x * 256 + threadIdx.x;  // N_*K_/8 threads
    const int o  = t >> 9;                          // 512 threads per output row
    const int ib = (t & 511) << 3;
    const int h  = o * HA + ib * HB + HC3;          // < 2^27, no overflow
    u16x8 out;
#pragma unroll
    for (int j = 0; j < 8; ++j) {
        const int idx = (h + j * HB) & (CBOOK - 1);
        float v = cb[idx];
        v = ((o ^ (ib + j)) & 1) ? -v : v;
        out[j] = f2bf(v);
    }
    *reinterpret_cast<u16x8*>(&W[(size_t)o * K_ + ib]) = out;
}

// ---------------------------------------------------------------------------
// x fp32 -> bf16 streaming conversion (128MB read + 64MB write)
// ---------------------------------------------------------------------------
__global__ __launch_bounds__(256) void conv_x_kernel(const float* __restrict__ x,
                                                     unsigned short* __restrict__ xb) {
    const size_t t = (size_t)blockIdx.x * 256 + threadIdx.x;   // M_*K_/8
    const float4* p = reinterpret_cast<const float4*>(x) + t * 2;
    const float4 a = p[0], b = p[1];
    u16x8 out;
    out[0] = f2bf(a.x); out[1] = f2bf(a.y); out[2] = f2bf(a.z); out[3] = f2bf(a.w);
    out[4] = f2bf(b.x); out[5] = f2bf(b.y); out[6] = f2bf(b.z); out[7] = f2bf(b.w);
    reinterpret_cast<u16x8*>(xb)[t] = out;
}

// ---------------------------------------------------------------------------
// m97-structure bf16 GEMM: C[M][N] = A[M][K] * W[N][K]^T + bias
// 128x128 tile, BK=32, 4 waves, each wave a 64x64 subtile = 4x4 MFMA 16x16x32.
// LDS tiles unpadded (global_load_lds requires lane-contiguous layout).
// ---------------------------------------------------------------------------
template <bool PRECONV>
__global__ __launch_bounds__(256) void gemm_kernel(const void* __restrict__ Asrc,
                                                   const unsigned short* __restrict__ W,
                                                   const float* __restrict__ bias,
                                                   float* __restrict__ C) {
    __shared__ __align__(16) unsigned short ldsA[BM * BK];  // 8 KB
    __shared__ __align__(16) unsigned short ldsB[BN * BK];  // 8 KB

    const int tid  = threadIdx.x;
    const int lane = tid & 63;
    const int wv   = tid >> 6;      // wave 0..3
    const int wm   = wv >> 1;       // wave row (0..1)
    const int wn   = wv & 1;        // wave col (0..1)
    const int m0 = blockIdx.y * BM;
    const int n0 = blockIdx.x * BN;

    const int quad = lane >> 4;     // 0..3
    const int l16  = lane & 15;

    f32x4 acc[4][4] = {};

    for (int k0 = 0; k0 < K_; k0 += BK) {
        // ---- stage B tile (128 rows of W x 32 k) via async global->LDS, 16B/lane
        {
            const unsigned short* gB = W + (size_t)n0 * K_ + k0;
#pragma unroll
            for (int r = 0; r < 2; ++r) {
                const int rowb = r * 64 + wv * 16;  // wave-uniform
                const unsigned short* src =
                    gB + (size_t)(rowb + (lane >> 2)) * K_ + (lane & 3) * 8;
                __builtin_amdgcn_global_load_lds((gbl_void_t*)src,
                                                 (lds_void_t*)&ldsB[rowb * BK], 16, 0, 0);
            }
        }
        // ---- stage A tile
        if constexpr (PRECONV) {
            const unsigned short* gA =
                (const unsigned short*)Asrc + (size_t)m0 * K_ + k0;
#pragma unroll
            for (int r = 0; r < 2; ++r) {
                const int rowb = r * 64 + wv * 16;
                const unsigned short* src =
                    gA + (size_t)(rowb + (lane >> 2)) * K_ + (lane & 3) * 8;
                __builtin_amdgcn_global_load_lds((gbl_void_t*)src,
                                                 (lds_void_t*)&ldsA[rowb * BK], 16, 0, 0);
            }
        } else {
            // fused fp32->bf16 conversion during staging (ws too small for xb)
            const float* xf = (const float*)Asrc;
            const int arow = tid >> 1;
            const int acol = (tid & 1) * 16;
            const float4* src = reinterpret_cast<const float4*>(
                xf + (size_t)(m0 + arow) * K_ + k0 + acol);
            const float4 v0 = src[0], v1 = src[1], v2 = src[2], v3 = src[3];
            u16x8 o0, o1;
            o0[0] = f2bf(v0.x); o0[1] = f2bf(v0.y); o0[2] = f2bf(v0.z); o0[3] = f2bf(v0.w);
            o0[4] = f2bf(v1.x); o0[5] = f2bf(v1.y); o0[6] = f2bf(v1.z); o0[7] = f2bf(v1.w);
            o1[0] = f2bf(v2.x); o1[1] = f2bf(v2.y); o1[2] = f2bf(v2.z); o1[3] = f2bf(v2.w);
            o1[4] = f2bf(v3.x); o1[5] = f2bf(v3.y); o1[6] = f2bf(v3.z); o1[7] = f2bf(v3.w);
            *reinterpret_cast<u16x8*>(&ldsA[arow * BK + acol]) = o0;
            *reinterpret_cast<u16x8*>(&ldsA[arow * BK + acol + 8]) = o1;
        }
        __syncthreads();   // compiler drains vmcnt before s_barrier

        // ---- 16 MFMA on the tile
        bf16x8 af[4], bfr[4];
        const int ka = quad * 8;   // this lane's k-offset within BK
#pragma unroll
        for (int mt = 0; mt < 4; ++mt)
            af[mt] = *reinterpret_cast<const bf16x8*>(
                &ldsA[(wm * 64 + mt * 16 + l16) * BK + ka]);
#pragma unroll
        for (int nt = 0; nt < 4; ++nt)
            bfr[nt] = *reinterpret_cast<const bf16x8*>(
                &ldsB[(wn * 64 + nt * 16 + l16) * BK + ka]);
#pragma unroll
        for (int mt = 0; mt < 4; ++mt)
#pragma unroll
            for (int nt = 0; nt < 4; ++nt)
                acc[mt][nt] = __builtin_amdgcn_mfma_f32_16x16x32_bf16(
                    af[mt], bfr[nt], acc[mt][nt], 0, 0, 0);

        __syncthreads();
    }

    // ---- epilogue: C/D layout col=lane&15, row=quad*4+r (m89/m91-verified)
#pragma unroll
    for (int nt = 0; nt < 4; ++nt) {
        const int col = n0 + wn * 64 + nt * 16 + l16;
        const float bv = bias[col];
#pragma unroll
        for (int mt = 0; mt < 4; ++mt) {
            const int rowb = m0 + wm * 64 + mt * 16 + quad * 4;
#pragma unroll
            for (int r = 0; r < 4; ++r)
                C[(size_t)(rowb + r) * N_ + col] = acc[mt][nt][r] + bv;
        }
    }
}

// ---------------------------------------------------------------------------
// Correctness-insurance fallback (only if ws_size < 32MB; slow but exact)
// ---------------------------------------------------------------------------
__global__ __launch_bounds__(256) void naive_kernel(const float* __restrict__ x,
                                                    const float* __restrict__ cb,
                                                    const float* __restrict__ bias,
                                                    float* __restrict__ out) {
    const size_t t = (size_t)blockIdx.x * 256 + threadIdx.x;
    const int row = (int)(t / N_);
    const int col = (int)(t % N_);
    float s = bias[col];
    const float* xr = x + (size_t)row * K_;
    const int h = col * HA + HC3;
    for (int i = 0; i < K_; ++i) {
        float v = cb[(h + i * HB) & (CBOOK - 1)];
        s += xr[i] * (((col ^ i) & 1) ? -v : v);
    }
    out[t] = s;
}

extern "C" void kernel_launch(void* const* d_in, const int* in_sizes, int n_in,
                              void* d_out, int out_size, void* d_ws, size_t ws_size,
                              hipStream_t stream) {
    const float* x    = (const float*)d_in[0];
    const float* cb   = (const float*)d_in[1];
    const float* bias = (const float*)d_in[2];
    float* out = (float*)d_out;

    const size_t wBytes = (size_t)N_ * K_ * sizeof(unsigned short);  // 32 MiB
    const size_t xBytes = (size_t)M_ * K_ * sizeof(unsigned short);  // 64 MiB

    if (ws_size >= wBytes + xBytes) {
        unsigned short* W  = (unsigned short*)d_ws;
        unsigned short* xb = (unsigned short*)((char*)d_ws + wBytes);
        gen_w_kernel<<<N_ * K_ / 8 / 256, 256, 0, stream>>>(cb, W);
        conv_x_kernel<<<M_ * K_ / 8 / 256, 256, 0, stream>>>(x, xb);
        gemm_kernel<true><<<dim3(N_ / BN, M_ / BM), 256, 0, stream>>>(
            (const void*)xb, W, bias, out);
    } else if (ws_size >= wBytes) {
        unsigned short* W = (unsigned short*)d_ws;
        gen_w_kernel<<<N_ * K_ / 8 / 256, 256, 0, stream>>>(cb, W);
        gemm_kernel<false><<<dim3(N_ / BN, M_ / BM), 256, 0, stream>>>(
            (const void*)x, W, bias, out);
    } else {
        naive_kernel<<<(int)((size_t)M_ * N_ / 256), 256, 0, stream>>>(x, cb, bias, out);
    }
}

// Round 2
// 542.664 us; speedup vs baseline: 1.0128x; 1.0128x over previous
//
#include <hip/hip_runtime.h>
#include <hip/hip_bf16.h>

// Problem constants (fixed by the reference)
constexpr int M_ = 8192;      // batch
constexpr int N_ = 4096;      // out_dim
constexpr int K_ = 4096;      // in_dim
constexpr int CBOOK = 65536;
constexpr int HA = 10007, HB = 20011;
constexpr int HC3 = 3 * 40009;     // 120027
// sign hash: all constants odd => sign = +1 iff (o+i) even

constexpr int BM = 128, BN = 128, BK = 64;

using bf16x8 = __bf16 __attribute__((ext_vector_type(8)));
using f32x4  = float __attribute__((ext_vector_type(4)));
using u16x8  = unsigned short __attribute__((ext_vector_type(8)));

typedef __attribute__((address_space(3))) void lds_void_t;
typedef const __attribute__((address_space(1))) void gbl_void_t;

static __device__ __forceinline__ unsigned short f2bf(float f) {
    __bf16 h = (__bf16)f;   // RNE on gfx950
    return __builtin_bit_cast(unsigned short, h);
}

// ---------------------------------------------------------------------------
// Merged prologue:
//   blocks [0, GENB)         : W[o][i] = sign * codebook[(o*HA+i*HB+HC3)&0xFFFF]
//   blocks [GENB, GENB+CONVB): x fp32 -> bf16 streaming conversion
// ---------------------------------------------------------------------------
constexpr int GENB  = N_ * K_ / 8 / 256;   // 8192
constexpr int CONVB = M_ * K_ / 8 / 256;   // 16384

__global__ __launch_bounds__(256) void prep_kernel(const float* __restrict__ x,
                                                   const float* __restrict__ cb,
                                                   unsigned short* __restrict__ W,
                                                   unsigned short* __restrict__ xb) {
    const int b = blockIdx.x;
    if (b < GENB) {
        const int t  = b * 256 + threadIdx.x;
        const int o  = t >> 9;                      // 512 threads per output row
        const int ib = (t & 511) << 3;
        const int h  = o * HA + ib * HB + HC3;      // < 2^27, no overflow
        u16x8 out;
#pragma unroll
        for (int j = 0; j < 8; ++j) {
            const int idx = (h + j * HB) & (CBOOK - 1);
            float v = cb[idx];
            v = ((o ^ (ib + j)) & 1) ? -v : v;
            out[j] = f2bf(v);
        }
        *reinterpret_cast<u16x8*>(&W[(size_t)o * K_ + ib]) = out;
    } else {
        const size_t t = (size_t)(b - GENB) * 256 + threadIdx.x;
        const float4* p = reinterpret_cast<const float4*>(x) + t * 2;
        const float4 a = p[0], c = p[1];
        u16x8 out;
        out[0] = f2bf(a.x); out[1] = f2bf(a.y); out[2] = f2bf(a.z); out[3] = f2bf(a.w);
        out[4] = f2bf(c.x); out[5] = f2bf(c.y); out[6] = f2bf(c.z); out[7] = f2bf(c.w);
        reinterpret_cast<u16x8*>(xb)[t] = out;
    }
}

// ---------------------------------------------------------------------------
// bf16 GEMM: C[M][N] = A[M][K] * W[N][K]^T + bias
// 128x128 tile, BK=64, 4 waves, each wave a 64x64 subtile = 4x4 MFMA 16x16x32
// per 32-k halfstep (2 halfsteps/iter, 32 MFMA per barrier pair).
// LDS is XOR-swizzled in 16B column blocks: LDS[row][c] = G[row][c ^ (row&7)].
// This keeps the global_load_lds wave-uniform-base + lane*16 constraint (we
// permute SOURCE addresses per lane) and makes frag ds_read_b128 2-way-max
// bank aliasing (free, m136) instead of 8-way.
// ---------------------------------------------------------------------------
__global__ __launch_bounds__(256) void gemm_kernel(const unsigned short* __restrict__ A,
                                                   const unsigned short* __restrict__ W,
                                                   const float* __restrict__ bias,
                                                   float* __restrict__ C) {
    __shared__ __align__(16) unsigned short ldsA[BM * BK];  // 16 KB
    __shared__ __align__(16) unsigned short ldsB[BN * BK];  // 16 KB

    const int tid  = threadIdx.x;
    const int lane = tid & 63;
    const int wv   = tid >> 6;      // wave 0..3
    const int wm   = wv >> 1;       // wave row (0..1)
    const int wn   = wv & 1;        // wave col (0..1)
    const int m0 = blockIdx.y * BM;
    const int n0 = blockIdx.x * BN;

    const int quad = lane >> 4;     // 0..3
    const int l16  = lane & 15;
    const int lr = lane >> 3;       // staging: row within 8-row group (0..7)
    const int lc = lane & 7;        // staging: 16B block within 64-col row
    const int scol = (lc ^ lr) * 8; // swizzled source column (elements)
    const int sw   = l16 & 7;       // frag-read swizzle key

    f32x4 acc[4][4] = {};

    for (int k0 = 0; k0 < K_; k0 += BK) {
        // ---- stage A and B tiles (128 x 64 bf16 each) async, 16B/lane.
        // instruction r covers rows [rowb, rowb+8); LDS dest rowb*BK*2 bytes
        // + lane*16 == row (rowb+lr), block lc.  Source col-block lc^lr keeps
        // the xor-swizzle invariant ((rowb+lr)&7 == lr since rowb % 8 == 0).
        {
            const unsigned short* gA = A + (size_t)m0 * K_ + k0;
            const unsigned short* gB = W + (size_t)n0 * K_ + k0;
#pragma unroll
            for (int r = 0; r < 4; ++r) {
                const int rowb = wv * 32 + r * 8;   // wave-uniform
                const unsigned short* srcA = gA + (size_t)(rowb + lr) * K_ + scol;
                const unsigned short* srcB = gB + (size_t)(rowb + lr) * K_ + scol;
                __builtin_amdgcn_global_load_lds((gbl_void_t*)srcA,
                                                 (lds_void_t*)&ldsA[rowb * BK], 16, 0, 0);
                __builtin_amdgcn_global_load_lds((gbl_void_t*)srcB,
                                                 (lds_void_t*)&ldsB[rowb * BK], 16, 0, 0);
            }
        }
        __syncthreads();   // compiler drains vmcnt before s_barrier

        // ---- 32 MFMA on the tile (2 k-halfsteps of 16)
#pragma unroll
        for (int kk = 0; kk < 2; ++kk) {
            bf16x8 af[4], bfr[4];
            const int blk = ((kk * 4 + quad) ^ sw) * 8;  // swizzled 16B block
#pragma unroll
            for (int mt = 0; mt < 4; ++mt)
                af[mt] = *reinterpret_cast<const bf16x8*>(
                    &ldsA[(wm * 64 + mt * 16 + l16) * BK + blk]);
#pragma unroll
            for (int nt = 0; nt < 4; ++nt)
                bfr[nt] = *reinterpret_cast<const bf16x8*>(
                    &ldsB[(wn * 64 + nt * 16 + l16) * BK + blk]);
#pragma unroll
            for (int mt = 0; mt < 4; ++mt)
#pragma unroll
                for (int nt = 0; nt < 4; ++nt)
                    acc[mt][nt] = __builtin_amdgcn_mfma_f32_16x16x32_bf16(
                        af[mt], bfr[nt], acc[mt][nt], 0, 0, 0);
        }
        __syncthreads();
    }

    // ---- epilogue: C/D layout col=lane&15, row=quad*4+r (m89/m91-verified)
#pragma unroll
    for (int nt = 0; nt < 4; ++nt) {
        const int col = n0 + wn * 64 + nt * 16 + l16;
        const float bv = bias[col];
#pragma unroll
        for (int mt = 0; mt < 4; ++mt) {
            const int rowb = m0 + wm * 64 + mt * 16 + quad * 4;
#pragma unroll
            for (int r = 0; r < 4; ++r)
                C[(size_t)(rowb + r) * N_ + col] = acc[mt][nt][r] + bv;
        }
    }
}

// ---------------------------------------------------------------------------
// Correctness-insurance fallback (only if ws too small; slow but exact)
// ---------------------------------------------------------------------------
__global__ __launch_bounds__(256) void naive_kernel(const float* __restrict__ x,
                                                    const float* __restrict__ cb,
                                                    const float* __restrict__ bias,
                                                    float* __restrict__ out) {
    const size_t t = (size_t)blockIdx.x * 256 + threadIdx.x;
    const int row = (int)(t / N_);
    const int col = (int)(t % N_);
    float s = bias[col];
    const float* xr = x + (size_t)row * K_;
    const int h = col * HA + HC3;
    for (int i = 0; i < K_; ++i) {
        float v = cb[(h + i * HB) & (CBOOK - 1)];
        s += xr[i] * (((col ^ i) & 1) ? -v : v);
    }
    out[t] = s;
}

extern "C" void kernel_launch(void* const* d_in, const int* in_sizes, int n_in,
                              void* d_out, int out_size, void* d_ws, size_t ws_size,
                              hipStream_t stream) {
    const float* x    = (const float*)d_in[0];
    const float* cb   = (const float*)d_in[1];
    const float* bias = (const float*)d_in[2];
    float* out = (float*)d_out;

    const size_t wBytes = (size_t)N_ * K_ * sizeof(unsigned short);  // 32 MiB
    const size_t xBytes = (size_t)M_ * K_ * sizeof(unsigned short);  // 64 MiB

    if (ws_size >= wBytes + xBytes) {
        unsigned short* W  = (unsigned short*)d_ws;
        unsigned short* xb = (unsigned short*)((char*)d_ws + wBytes);
        prep_kernel<<<GENB + CONVB, 256, 0, stream>>>(x, cb, W, xb);
        gemm_kernel<<<dim3(N_ / BN, M_ / BM), 256, 0, stream>>>(xb, W, bias, out);
    } else {
        naive_kernel<<<(int)((size_t)M_ * N_ / 256), 256, 0, stream>>>(x, cb, bias, out);
    }
}

// Round 3
// 524.934 us; speedup vs baseline: 1.0470x; 1.0338x over previous
//
#include <hip/hip_runtime.h>
#include <hip/hip_bf16.h>

// Problem constants (fixed by the reference)
constexpr int M_ = 8192;      // batch
constexpr int N_ = 4096;      // out_dim
constexpr int K_ = 4096;      // in_dim
constexpr int CBOOK = 65536;
constexpr int HA = 10007, HB = 20011;
constexpr int HC3 = 3 * 40009;     // 120027
// sign hash: all constants odd => sign = +1 iff (o+i) even

// GEMM tiling: block 256x128, 4 waves stacked (wave tile 64x128), BK=64.
// A (x, bf16) goes through double-buffered LDS (amp-1: each wave reads only
// its own rows).  B (W) is read straight global->VGPR from a fragment-flat
// layout we generate ourselves -> zero LDS traffic for B.
constexpr int BM = 256, BN = 128, BK = 64;
constexpr int KITERS = K_ / BK;            // 64

using bf16x8 = __bf16 __attribute__((ext_vector_type(8)));
using f32x4  = float __attribute__((ext_vector_type(4)));
using u16x8  = unsigned short __attribute__((ext_vector_type(8)));

typedef __attribute__((address_space(3))) void lds_void_t;
typedef const __attribute__((address_space(1))) void gbl_void_t;

static __device__ __forceinline__ unsigned short f2bf(float f) {
    __bf16 h = (__bf16)f;   // RNE on gfx950
    return __builtin_bit_cast(unsigned short, h);
}

// ---------------------------------------------------------------------------
// Merged prologue.
//   blocks [0, GENB): W in MFMA B-fragment-flat order:
//     Wf[((ntile*128 + ktile)*64 + lane)*8 + j]
//       = sign * cb[hash(n, k)],  n = ntile*16 + (lane&15),
//                                 k = ktile*32 + (lane>>4)*8 + j
//     (matches mfma_f32_16x16x32_bf16 B-operand: lane holds W[n][k..k+8))
//   blocks [GENB, GENB+CONVB): x fp32 -> bf16 row-major (A staging source)
// ---------------------------------------------------------------------------
constexpr int GENB  = N_ * K_ / 8 / 256;   // 8192
constexpr int CONVB = M_ * K_ / 8 / 256;   // 16384

__global__ __launch_bounds__(256) void prep_kernel(const float* __restrict__ x,
                                                   const float* __restrict__ cb,
                                                   unsigned short* __restrict__ Wf,
                                                   unsigned short* __restrict__ xb) {
    const int b = blockIdx.x;
    if (b < GENB) {
        const int t     = b * 256 + threadIdx.x;   // [0, 2^21)
        const int lane  = t & 63;
        const int ktile = (t >> 6) & 127;
        const int ntile = t >> 13;
        const int n  = (ntile << 4) + (lane & 15);
        const int kb = (ktile << 5) + ((lane >> 4) << 3);
        const int h  = n * HA + kb * HB + HC3;     // < 2^27, no overflow
        u16x8 out;
#pragma unroll
        for (int j = 0; j < 8; ++j) {
            const int idx = (h + j * HB) & (CBOOK - 1);
            float v = cb[idx];
            v = ((n ^ (kb + j)) & 1) ? -v : v;
            out[j] = f2bf(v);
        }
        *reinterpret_cast<u16x8*>(&Wf[(size_t)t * 8]) = out;   // coalesced
    } else {
        const size_t t = (size_t)(b - GENB) * 256 + threadIdx.x;
        const float4* p = reinterpret_cast<const float4*>(x) + t * 2;
        const float4 a = p[0], c = p[1];
        u16x8 out;
        out[0] = f2bf(a.x); out[1] = f2bf(a.y); out[2] = f2bf(a.z); out[3] = f2bf(a.w);
        out[4] = f2bf(c.x); out[5] = f2bf(c.y); out[6] = f2bf(c.z); out[7] = f2bf(c.w);
        reinterpret_cast<u16x8*>(xb)[t] = out;
    }
}

// ---------------------------------------------------------------------------
// GEMM: C[M][N] = A[M][K] * W[N][K]^T + bias
// ---------------------------------------------------------------------------
__global__ __launch_bounds__(256, 2) void gemm_kernel(
        const unsigned short* __restrict__ A,    // xb row-major [M][K]
        const unsigned short* __restrict__ Wf,   // fragment-flat W
        const float* __restrict__ bias,
        float* __restrict__ C) {
    __shared__ __align__(16) unsigned short ldsA[2][BM * BK];  // 2 x 32 KB

    const int tid  = threadIdx.x;
    const int lane = tid & 63;
    const int wv   = tid >> 6;      // wave 0..3 -> A row strip wv*64
    const int m0 = blockIdx.y * BM;
    const int n0 = blockIdx.x * BN;

    const int quad = lane >> 4;     // 0..3
    const int l16  = lane & 15;
    const int lr = lane >> 3;       // staging: row in 8-row group
    const int lc = lane & 7;        // staging: 16B block in 128B row
    const int scol = (lc ^ lr) * 8; // xor-swizzled source column (elements)
    const int sw   = l16 & 7;       // frag-read swizzle key (row&7 == l16&7)

    // lane's global A base (row m0 + lr; inst r adds wv*64 + r*8 rows)
    const unsigned short* aLane = A + (size_t)(m0 + lr) * K_ + scol;
    // lane's flat-W base
    const unsigned short* wLane = Wf + (size_t)lane * 8;
    const int ntile0 = n0 >> 4;

    f32x4 acc[4][8] = {};           // [mt][nt] -> 128 VGPRs

    // stage k-iter 0 into buffer 0
#pragma unroll
    for (int r = 0; r < 8; ++r) {
        const int rowb = wv * 64 + r * 8;   // wave-uniform
        __builtin_amdgcn_global_load_lds(
            (gbl_void_t*)(aLane + (size_t)rowb * K_),
            (lds_void_t*)&ldsA[0][rowb * BK], 16, 0, 0);
    }

    for (int i = 0; i < KITERS; ++i) {
        __syncthreads();            // A(i) staged; all waves done with buf^1
        const int buf = i & 1;

        // stage A(i+1) into the other buffer (overlaps this iter's MFMAs)
        if (i + 1 < KITERS) {
            const unsigned short* aNext = aLane + (size_t)(i + 1) * BK;
#pragma unroll
            for (int r = 0; r < 8; ++r) {
                const int rowb = wv * 64 + r * 8;
                __builtin_amdgcn_global_load_lds(
                    (gbl_void_t*)(aNext + (size_t)rowb * K_),
                    (lds_void_t*)&ldsA[buf ^ 1][rowb * BK], 16, 0, 0);
            }
        }

        // B fragments for both k32 halfsteps, straight from L2 (1KB/load)
        bf16x8 bfr[2][8];
#pragma unroll
        for (int kk = 0; kk < 2; ++kk)
#pragma unroll
            for (int nt = 0; nt < 8; ++nt)
                bfr[kk][nt] = *reinterpret_cast<const bf16x8*>(
                    wLane + (((size_t)(ntile0 + nt) << 7) + i * 2 + kk) * 512);

#pragma unroll
        for (int kk = 0; kk < 2; ++kk) {
            bf16x8 af[4];
            const int blk = ((kk * 4 + quad) ^ sw) * 8;  // swizzled 16B block
#pragma unroll
            for (int mt = 0; mt < 4; ++mt)
                af[mt] = *reinterpret_cast<const bf16x8*>(
                    &ldsA[buf][(wv * 64 + mt * 16 + l16) * BK + blk]);
#pragma unroll
            for (int mt = 0; mt < 4; ++mt)
#pragma unroll
                for (int nt = 0; nt < 8; ++nt)
                    acc[mt][nt] = __builtin_amdgcn_mfma_f32_16x16x32_bf16(
                        af[mt], bfr[kk][nt], acc[mt][nt], 0, 0, 0);
        }
    }

    // epilogue: C/D layout col=lane&15, row=quad*4+r (m89/m91-verified)
#pragma unroll
    for (int nt = 0; nt < 8; ++nt) {
        const int col = n0 + nt * 16 + l16;
        const float bv = bias[col];
#pragma unroll
        for (int mt = 0; mt < 4; ++mt) {
            const int rowb = m0 + wv * 64 + mt * 16 + quad * 4;
#pragma unroll
            for (int r = 0; r < 4; ++r)
                C[(size_t)(rowb + r) * N_ + col] = acc[mt][nt][r] + bv;
        }
    }
}

// ---------------------------------------------------------------------------
// Correctness-insurance fallback (only if ws too small; slow but exact)
// ---------------------------------------------------------------------------
__global__ __launch_bounds__(256) void naive_kernel(const float* __restrict__ x,
                                                    const float* __restrict__ cb,
                                                    const float* __restrict__ bias,
                                                    float* __restrict__ out) {
    const size_t t = (size_t)blockIdx.x * 256 + threadIdx.x;
    const int row = (int)(t / N_);
    const int col = (int)(t % N_);
    float s = bias[col];
    const float* xr = x + (size_t)row * K_;
    const int h = col * HA + HC3;
    for (int i = 0; i < K_; ++i) {
        float v = cb[(h + i * HB) & (CBOOK - 1)];
        s += xr[i] * (((col ^ i) & 1) ? -v : v);
    }
    out[t] = s;
}

extern "C" void kernel_launch(void* const* d_in, const int* in_sizes, int n_in,
                              void* d_out, int out_size, void* d_ws, size_t ws_size,
                              hipStream_t stream) {
    const float* x    = (const float*)d_in[0];
    const float* cb   = (const float*)d_in[1];
    const float* bias = (const float*)d_in[2];
    float* out = (float*)d_out;

    const size_t wBytes = (size_t)N_ * K_ * sizeof(unsigned short);  // 32 MiB
    const size_t xBytes = (size_t)M_ * K_ * sizeof(unsigned short);  // 64 MiB

    if (ws_size >= wBytes + xBytes) {
        unsigned short* Wf = (unsigned short*)d_ws;
        unsigned short* xb = (unsigned short*)((char*)d_ws + wBytes);
        prep_kernel<<<GENB + CONVB, 256, 0, stream>>>(x, cb, Wf, xb);
        // gridDim.x = 32 n-strips: XCD = linear%8 = x%8 -> each XCD's W slice
        // is 4 strips * 1MB = 4MB = its L2. B frag stream stays L2-resident.
        gemm_kernel<<<dim3(N_ / BN, M_ / BM), 256, 0, stream>>>(xb, Wf, bias, out);
    } else {
        naive_kernel<<<(int)((size_t)M_ * N_ / 256), 256, 0, stream>>>(x, cb, bias, out);
    }
}